// Round 3
// baseline (1217.987 us; speedup 1.0000x reference)
//
#include <hip/hip_runtime.h>
#include <hip/hip_bf16.h>

#define IN_F 128
#define HF 256
#define BN_EPS 1e-5f
#define SELU_SCALE 1.0507009873554805f
#define SELU_ALPHA 1.6732632423543772f

typedef __attribute__((ext_vector_type(8))) short short8;
typedef __attribute__((ext_vector_type(4))) short short4v;
typedef __attribute__((ext_vector_type(8))) _Float16 half8;
typedef __attribute__((ext_vector_type(4))) float f32x4;

__device__ __forceinline__ short f2h(float f) {
    _Float16 h = (_Float16)f;               // RTN fp32->fp16
    return __builtin_bit_cast(short, h);
}

__device__ __forceinline__ float selu_f(float x) {
    return SELU_SCALE * (x > 0.f ? x : SELU_ALPHA * expm1f(x));
}

// A-LDS: [64 rows][256 fp16], row stride 512B. XOR-swizzle bits 4-6 of the
// byte offset by (row&7)<<4 so the 16 lanes of an a-frag ds_read_b128 (rows
// r..r+15, same k) hit 8 distinct 16B slots -> 2-way aliasing only (free).
__device__ __forceinline__ int swzA(int row, int byteInRow) {
    return row * 512 + (byteInRow ^ ((row & 7) << 4));
}

// Fold BN into weights: W'[n][k] = W[n][k]*s[n], b'[n] = (b[n]-m[n])*s[n]+beta[n].
// Store W' fp16 row-major [n][k] per layer (the exact B-fragment layout).
__global__ void prep_kernel(const float* __restrict__ W0, const float* __restrict__ b0,
                            const float* __restrict__ g0, const float* __restrict__ beta0,
                            const float* __restrict__ m0, const float* __restrict__ v0,
                            const float* __restrict__ Ws, const float* __restrict__ bs,
                            const float* __restrict__ gs, const float* __restrict__ betas,
                            const float* __restrict__ ms, const float* __restrict__ vs,
                            unsigned short* __restrict__ Wh, float* __restrict__ biasArr) {
    int b = blockIdx.x;
    int layer = b >> 8;
    int n = b & 255;
    int k = threadIdx.x;
    const float *W, *bb, *g, *be, *m, *v;
    if (layer == 0) { W = W0; bb = b0; g = g0; be = beta0; m = m0; v = v0; }
    else {
        int i = layer - 1;
        W = Ws + (size_t)i * HF * HF; bb = bs + i * HF; g = gs + i * HF;
        be = betas + i * HF; m = ms + i * HF; v = vs + i * HF;
    }
    float s = g[n] * rsqrtf(v[n] + BN_EPS);
    Wh[(size_t)layer * HF * HF + n * HF + k] = (unsigned short)f2h(W[n * HF + k] * s);
    if (k == 0) biasArr[layer * HF + n] = (bb[n] - m[n]) * s + be[n];
}

__global__ void count_kernel(const int* __restrict__ dstI, int* __restrict__ cnt, int E) {
    int i = blockIdx.x * 256 + threadIdx.x;
    if (i < E) atomicAdd(cnt + dstI[i], 1);
}

__global__ void finalize_kernel(float* __restrict__ agg, const int* __restrict__ cnt) {
    int n = blockIdx.x;
    float c = fmaxf((float)cnt[n], 1.f);
    agg[(size_t)n * HF + threadIdx.x] = agg[(size_t)n * HF + threadIdx.x] / c;
}

// One block = 64 edges x all 256 output cols, 4 waves (wave = 64 rows x 64 cols,
// 4x4 frags of mfma_f32_16x16x32_f16). All 3 MLP layers chained through the
// 32KB A-LDS (gather-concat x -> h1 -> h2), weights read straight from L2.
// Epilogue: 16-row chunks staged via LDS -> full-row coalesced 1KB stores of h
// + fused atomicAdd scatter into agg.
__global__ __launch_bounds__(256, 3)
void fused_kernel(const float* __restrict__ x,
                  const int* __restrict__ dstI, const int* __restrict__ srcI,
                  const unsigned short* __restrict__ Wh,
                  const float* __restrict__ biasArr,
                  float* __restrict__ h, float* __restrict__ agg) {
    __shared__ __align__(16) char lds[64 * 512];   // 32 KB

    const int rowBase = blockIdx.x * 64;
    const int t = threadIdx.x;
    const int lane = t & 63;
    const int wc = t >> 6;          // wave -> 64-col slab
    const int lrow = lane & 15;
    const int lgrp = lane >> 4;     // 0..3
    const int lko = lgrp * 8;       // k offset (halfs) within 32-wide slice

    // ---- stage layer-1 A: concat(x[dst], x[src]) fp32 -> fp16, swizzled ----
#pragma unroll
    for (int i = 0; i < 16; ++i) {
        int f = t + i * 256;        // float4 slot: 64 rows x 64 float4
        int row = f >> 6;
        int seg = f & 63;           // 0-31: x[dst], 32-63: x[src]
        int e = rowBase + row;
        int idx = (seg < 32) ? dstI[e] : srcI[e];
        float4 v = *(const float4*)(x + (size_t)idx * IN_F + (seg & 31) * 4);
        short4v p;
        p[0] = f2h(v.x); p[1] = f2h(v.y); p[2] = f2h(v.z); p[3] = f2h(v.w);
        *(short4v*)&lds[swzA(row, seg * 8)] = p;
    }
    __syncthreads();

    f32x4 acc[4][4];
    const f32x4 zero = {0.f, 0.f, 0.f, 0.f};

#pragma unroll
    for (int L = 0; L < 3; ++L) {
        const unsigned short* Bl = Wh + (size_t)L * HF * HF;
#pragma unroll
        for (int mi = 0; mi < 4; ++mi)
#pragma unroll
            for (int ni = 0; ni < 4; ++ni) acc[mi][ni] = zero;

#pragma unroll
        for (int s = 0; s < 8; ++s) {        // K = 256 in 32-slices
            half8 b[4];
#pragma unroll
            for (int ni = 0; ni < 4; ++ni)
                b[ni] = *(const half8*)(Bl + (size_t)(wc * 64 + ni * 16 + lrow) * HF + s * 32 + lko);
#pragma unroll
            for (int mi = 0; mi < 4; ++mi) {
                half8 a = *(const half8*)&lds[swzA(mi * 16 + lrow, (s * 32 + lko) * 2)];
#pragma unroll
                for (int ni = 0; ni < 4; ++ni)
                    acc[mi][ni] = __builtin_amdgcn_mfma_f32_16x16x32_f16(a, b[ni], acc[mi][ni], 0, 0, 0);
            }
        }
        __syncthreads();                     // all waves done reading this layer's A

        if (L < 2) {
            float bc[4];
#pragma unroll
            for (int ni = 0; ni < 4; ++ni) bc[ni] = biasArr[L * HF + wc * 64 + ni * 16 + lrow];
#pragma unroll
            for (int mi = 0; mi < 4; ++mi)
#pragma unroll
                for (int ni = 0; ni < 4; ++ni)
#pragma unroll
                    for (int r = 0; r < 4; ++r) {
                        int row = mi * 16 + lgrp * 4 + r;
                        int col = wc * 64 + ni * 16 + lrow;
                        float val = selu_f(acc[mi][ni][r] + bc[ni]);
                        *(short*)&lds[swzA(row, col * 2)] = f2h(val);
                    }
            __syncthreads();                 // h_L ready as next layer's A
        }
    }

    // ---- epilogue: bias+SELU, stage 16-row chunks in LDS, coalesced stores ----
    float bc[4];
#pragma unroll
    for (int ni = 0; ni < 4; ++ni) bc[ni] = biasArr[2 * HF + wc * 64 + ni * 16 + lrow];
    float* eps = (float*)lds;                // [16][264] fp32 chunk
#pragma unroll
    for (int c = 0; c < 4; ++c) {            // chunk c <-> fragment row-block mi=c
#pragma unroll
        for (int ni = 0; ni < 4; ++ni)
#pragma unroll
            for (int r = 0; r < 4; ++r)
                eps[(lgrp * 4 + r) * 264 + wc * 64 + ni * 16 + lrow] =
                    selu_f(acc[c][ni][r] + bc[ni]);
        __syncthreads();
#pragma unroll
        for (int i = 0; i < 4; ++i) {
            int f = t + i * 256;             // 1024 float4 = 16 rows x 64 slots
            int r16 = f >> 6;
            int slot = f & 63;
            int e = rowBase + c * 16 + r16;
            f32x4 val = *(const f32x4*)&eps[r16 * 264 + slot * 4];
            *(f32x4*)&h[(size_t)e * HF + slot * 4] = val;
            int d = dstI[e];
            float* ap = agg + (size_t)d * HF + slot * 4;
            atomicAdd(ap + 0, val[0]);
            atomicAdd(ap + 1, val[1]);
            atomicAdd(ap + 2, val[2]);
            atomicAdd(ap + 3, val[3]);
        }
        __syncthreads();
    }
}

extern "C" void kernel_launch(void* const* d_in, const int* in_sizes, int n_in,
                              void* d_out, int out_size, void* d_ws, size_t ws_size,
                              hipStream_t stream) {
    const float* x     = (const float*)d_in[0];
    const int*   ei    = (const int*)d_in[1];
    const float* W0    = (const float*)d_in[2];
    const float* b0    = (const float*)d_in[3];
    const float* g0    = (const float*)d_in[4];
    const float* beta0 = (const float*)d_in[5];
    const float* m0    = (const float*)d_in[6];
    const float* v0    = (const float*)d_in[7];
    const float* Ws    = (const float*)d_in[8];
    const float* bs    = (const float*)d_in[9];
    const float* gs    = (const float*)d_in[10];
    const float* betas = (const float*)d_in[11];
    const float* ms    = (const float*)d_in[12];
    const float* vs    = (const float*)d_in[13];

    const int Nn = in_sizes[0] / IN_F;   // 20000
    const int E  = in_sizes[1] / 2;      // 320000

    float* agg  = (float*)d_out;
    float* hbuf = agg + (size_t)Nn * HF; // final h region of d_out

    // workspace: [0, 384K) fp16 folded weights; [+3K) folded biases; then counts
    unsigned short* Wh = (unsigned short*)d_ws;
    float* biasArr = (float*)((char*)d_ws + 3 * HF * HF * sizeof(unsigned short));
    int* cnt = (int*)((char*)d_ws + 3 * HF * HF * sizeof(unsigned short) + 3 * HF * sizeof(float));

    const int* srcI = ei;        // edge_index[0]
    const int* dstI = ei + E;    // edge_index[1]

    hipMemsetAsync(d_out, 0, (size_t)Nn * HF * sizeof(float), stream);  // agg accum
    hipMemsetAsync(cnt, 0, (size_t)Nn * sizeof(int), stream);

    prep_kernel<<<3 * HF, HF, 0, stream>>>(W0, b0, g0, beta0, m0, v0,
                                           Ws, bs, gs, betas, ms, vs, Wh, biasArr);
    count_kernel<<<(E + 255) / 256, 256, 0, stream>>>(dstI, cnt, E);

    fused_kernel<<<E / 64, 256, 0, stream>>>(x, dstI, srcI, Wh, biasArr, hbuf, agg);

    finalize_kernel<<<Nn, HF, 0, stream>>>(agg, cnt);
}

// Round 4
// 641.718 us; speedup vs baseline: 1.8980x; 1.8980x over previous
//
#include <hip/hip_runtime.h>
#include <hip/hip_bf16.h>

#define IN_F 128
#define HF 256
#define BN_EPS 1e-5f
#define SELU_SCALE 1.0507009873554805f
#define SELU_ALPHA 1.6732632423543772f

typedef __attribute__((ext_vector_type(8))) _Float16 half8;
typedef __attribute__((ext_vector_type(4))) short short4v;
typedef __attribute__((ext_vector_type(4))) float f32x4;

__device__ __forceinline__ short f2h(float f) {
    _Float16 h = (_Float16)f;               // RTNE fp32->fp16
    return __builtin_bit_cast(short, h);
}

__device__ __forceinline__ float selu_f(float x) {
    return SELU_SCALE * (x > 0.f ? x : SELU_ALPHA * expm1f(x));
}

// async global->LDS, 16B per lane; LDS dest = wave-uniform base + lane*16
__device__ __forceinline__ void gld_lds16(const void* g, void* l) {
    __builtin_amdgcn_global_load_lds(
        (const __attribute__((address_space(1))) unsigned int*)g,
        (__attribute__((address_space(3))) unsigned int*)l, 16, 0, 0);
}

// x fp32 -> fp16 (plain layout), stored in the agg region of d_out (dead until GEMM1 done)
__global__ void cvt_x_kernel(const float* __restrict__ x, unsigned short* __restrict__ x16, int n4) {
    int i = blockIdx.x * 256 + threadIdx.x;
    if (i < n4) {
        f32x4 v = ((const f32x4*)x)[i];
        short4v p;
        p[0] = f2h(v[0]); p[1] = f2h(v[1]); p[2] = f2h(v[2]); p[3] = f2h(v[3]);
        ((short4v*)x16)[i] = p;
    }
}

// Fold BN into weights; store fp16, XOR-swizzled within each 64-elem (128B) k-segment:
// element (n,k) stored at k ^ ((n&7)<<3). GEMM B-staging then loads LINEARLY via
// global_load_lds and the ds_read applies the same XOR -> conflict-free.
__global__ void prep_kernel(const float* __restrict__ W0, const float* __restrict__ b0,
                            const float* __restrict__ g0, const float* __restrict__ beta0,
                            const float* __restrict__ m0, const float* __restrict__ v0,
                            const float* __restrict__ Ws, const float* __restrict__ bs,
                            const float* __restrict__ gs, const float* __restrict__ betas,
                            const float* __restrict__ ms, const float* __restrict__ vs,
                            unsigned short* __restrict__ Wh, float* __restrict__ biasArr) {
    int b = blockIdx.x;
    int layer = b >> 8;
    int n = b & 255;
    int k = threadIdx.x;
    const float *W, *bb, *g, *be, *m, *v;
    if (layer == 0) { W = W0; bb = b0; g = g0; be = beta0; m = m0; v = v0; }
    else {
        int i = layer - 1;
        W = Ws + (size_t)i * HF * HF; bb = bs + i * HF; g = gs + i * HF;
        be = betas + i * HF; m = ms + i * HF; v = vs + i * HF;
    }
    float s = g[n] * rsqrtf(v[n] + BN_EPS);
    int ksw = k ^ ((n & 7) << 3);
    Wh[(size_t)layer * HF * HF + n * HF + ksw] = (unsigned short)f2h(W[n * HF + k] * s);
    if (k == 0) biasArr[layer * HF + n] = (bb[n] - m[n]) * s + be[n];
}

__global__ void count_kernel(const int* __restrict__ dstI, int* __restrict__ cnt, int E) {
    int i = blockIdx.x * 256 + threadIdx.x;
    if (i < E) atomicAdd(cnt + dstI[i], 1);
}

__global__ void finalize_kernel(float* __restrict__ agg, const int* __restrict__ cnt) {
    int n = blockIdx.x;
    float c = fmaxf((float)cnt[n], 1.f);
    agg[(size_t)n * HF + threadIdx.x] = agg[(size_t)n * HF + threadIdx.x] / c;
}

// One block = 128 edge-rows x ALL 256 cols (in-place safe), 512 thr = 8 waves (2x4),
// wave tile 64x64, 4x4 frags of mfma_f32_16x16x32_f16, BK=64 (4 k-steps).
// A/B staged via global_load_lds w16 from pre-swizzled sources; LDS linear.
// h1/h2 live as fp16 (XOR-swizzled) in the low 512B of each edge's 1KB fp32 slot.
// MODE 0: A = gather-concat x16 (swizzle folded into per-lane global addr) -> hh fp16
// MODE 1: A = hh -> hh (same-offset in-place)
// MODE 2: A = hh -> final h fp32 (plain, full 1KB rows) + atomic scatter into agg
template <int MODE>
__global__ __launch_bounds__(512)
void gemm_kernel(const unsigned short* __restrict__ x16,
                 const unsigned char* __restrict__ hhB,
                 const int* __restrict__ dstI, const int* __restrict__ srcI,
                 const unsigned short* __restrict__ Wh,   // this layer, swizzled
                 const float* __restrict__ biasArr,       // this layer
                 unsigned char* __restrict__ outB,
                 float* __restrict__ agg) {
    __shared__ __align__(16) unsigned char lds[49152];   // A:16K | B:32K ; epilogue reuses 32K

    const int rowBase = blockIdx.x * 128;
    const int t = threadIdx.x;
    const int lane = t & 63;
    const int w = t >> 6;           // 0..7
    const int wr = w >> 2;          // 0..1 : 64-row half
    const int wcol = w & 3;         // 0..3 : 64-col slab
    const int lrow = lane & 15;
    const int lgrp = lane >> 4;
    const int lko = lgrp * 8;       // k offset within 32-wide slice
    const int sub = lane & 7;       // 16B chunk within 128B row-segment
    const int r8 = lane >> 3;       // row within 8-row staging chunk

    f32x4 acc[4][4];
    const f32x4 zero = {0.f, 0.f, 0.f, 0.f};
#pragma unroll
    for (int mi = 0; mi < 4; ++mi)
#pragma unroll
        for (int ni = 0; ni < 4; ++ni) acc[mi][ni] = zero;

#pragma unroll
    for (int kk = 0; kk < 4; ++kk) {
        // ---- stage A (16KB = 16 x 1KB chunks; 2 per wave) ----
#pragma unroll
        for (int i = 0; i < 2; ++i) {
            int c = w * 2 + i;              // chunk 0..15
            int row = c * 8 + r8;           // tile row 0..127
            const unsigned char* g;
            if (MODE == 0) {
                int e = rowBase + row;
                int idx = (kk < 2 ? dstI : srcI)[e];
                g = (const unsigned char*)x16 + (size_t)idx * 256 + (kk & 1) * 128
                    + ((sub * 16) ^ ((row & 7) << 4));   // pre-swizzled gather
            } else {
                int e = rowBase + row;
                g = hhB + (size_t)e * 1024 + kk * 128 + sub * 16;  // data already swizzled
            }
            gld_lds16(g, lds + c * 1024);
        }
        // ---- stage B (32KB = 32 x 1KB chunks; 4 per wave) ----
#pragma unroll
        for (int i = 0; i < 4; ++i) {
            int c = w * 4 + i;              // chunk 0..31
            int n = c * 8 + r8;             // weight row 0..255
            const unsigned char* g = (const unsigned char*)Wh + (size_t)n * 512 + kk * 128 + sub * 16;
            gld_lds16(g, lds + 16384 + c * 1024);
        }
        __syncthreads();

        half8 af[4][2], bf[4][2];
#pragma unroll
        for (int mi = 0; mi < 4; ++mi)
#pragma unroll
            for (int kI = 0; kI < 2; ++kI) {
                int r = wr * 64 + mi * 16 + lrow;
                af[mi][kI] = *(const half8*)&lds[r * 128 + (((kI * 32 + lko) * 2) ^ ((r & 7) << 4))];
            }
#pragma unroll
        for (int ni = 0; ni < 4; ++ni)
#pragma unroll
            for (int kI = 0; kI < 2; ++kI) {
                int n = wcol * 64 + ni * 16 + lrow;
                bf[ni][kI] = *(const half8*)&lds[16384 + n * 128 + (((kI * 32 + lko) * 2) ^ ((n & 7) << 4))];
            }
#pragma unroll
        for (int kI = 0; kI < 2; ++kI)
#pragma unroll
            for (int mi = 0; mi < 4; ++mi)
#pragma unroll
                for (int ni = 0; ni < 4; ++ni)
                    acc[mi][ni] = __builtin_amdgcn_mfma_f32_16x16x32_f16(
                        af[mi][kI], bf[ni][kI], acc[mi][ni], 0, 0, 0);
        __syncthreads();
    }

    float bc[4];
#pragma unroll
    for (int ni = 0; ni < 4; ++ni) bc[ni] = biasArr[wcol * 64 + ni * 16 + lrow];

    if (MODE < 2) {
        // ---- fp16 swizzled out: 2 chunks of 64 rows (32KB stage) ----
#pragma unroll
        for (int cc = 0; cc < 2; ++cc) {
            __syncthreads();
            if (wr == cc) {
#pragma unroll
                for (int mi = 0; mi < 4; ++mi)
#pragma unroll
                    for (int ni = 0; ni < 4; ++ni)
#pragma unroll
                        for (int r = 0; r < 4; ++r) {
                            int lr = mi * 16 + lgrp * 4 + r;          // 0..63
                            int cg = wcol * 64 + ni * 16 + lrow;      // 0..255
                            float val = selu_f(acc[mi][ni][r] + bc[ni]);
                            int pos = (cg >> 6) * 128 + ((((cg & 63) * 2)) ^ ((lr & 7) << 4));
                            *(short*)&lds[lr * 512 + pos] = f2h(val);
                        }
            }
            __syncthreads();
#pragma unroll
            for (int i = 0; i < 4; ++i) {
                int f = t + i * 512;                  // 2048 x 16B
                int row = f >> 5, ch = f & 31;
                int e = rowBase + cc * 64 + row;
                f32x4 v = *(const f32x4*)&lds[row * 512 + ch * 16];
                *(f32x4*)(outB + (size_t)e * 1024 + ch * 16) = v;
            }
        }
    } else {
        // ---- fp32 plain out: 4 chunks of 32 rows (32KB stage) + atomics ----
#pragma unroll
        for (int cc = 0; cc < 4; ++cc) {
            __syncthreads();
            if (wr == (cc >> 1)) {
#pragma unroll
                for (int m2 = 0; m2 < 2; ++m2) {
                    int mi = (cc & 1) * 2 + m2;
#pragma unroll
                    for (int ni = 0; ni < 4; ++ni)
#pragma unroll
                        for (int r = 0; r < 4; ++r) {
                            int lr = m2 * 16 + lgrp * 4 + r;          // 0..31
                            int cg = wcol * 64 + ni * 16 + lrow;
                            float val = selu_f(acc[mi][ni][r] + bc[ni]);
                            *(float*)&lds[lr * 1024 + cg * 4] = val;
                            int e = rowBase + cc * 32 + lr;
                            atomicAdd(agg + (size_t)dstI[e] * HF + cg, val);
                        }
                }
            }
            __syncthreads();
#pragma unroll
            for (int i = 0; i < 4; ++i) {
                int f = t + i * 512;                  // 2048 x 16B
                int row = f >> 6, ch = f & 63;        // 32 rows x 64 chunks
                int e = rowBase + cc * 32 + row;
                f32x4 v = *(const f32x4*)&lds[row * 1024 + ch * 16];
                *(f32x4*)(outB + (size_t)e * 1024 + ch * 16) = v;
            }
        }
    }
}

extern "C" void kernel_launch(void* const* d_in, const int* in_sizes, int n_in,
                              void* d_out, int out_size, void* d_ws, size_t ws_size,
                              hipStream_t stream) {
    const float* x     = (const float*)d_in[0];
    const int*   ei    = (const int*)d_in[1];
    const float* W0    = (const float*)d_in[2];
    const float* b0    = (const float*)d_in[3];
    const float* g0    = (const float*)d_in[4];
    const float* beta0 = (const float*)d_in[5];
    const float* m0    = (const float*)d_in[6];
    const float* v0    = (const float*)d_in[7];
    const float* Ws    = (const float*)d_in[8];
    const float* bs    = (const float*)d_in[9];
    const float* gs    = (const float*)d_in[10];
    const float* betas = (const float*)d_in[11];
    const float* ms    = (const float*)d_in[12];
    const float* vs    = (const float*)d_in[13];

    const int Nn = in_sizes[0] / IN_F;   // 20000
    const int E  = in_sizes[1] / 2;      // 320000

    float* agg  = (float*)d_out;
    float* hptr = agg + (size_t)Nn * HF;             // h region: E slots of 1KB
    unsigned char* hhB = (unsigned char*)hptr;       // fp16 intermediates in low 512B of each slot

    // ws: Wh (384KB swizzled fp16) | biasArr (3KB) | cnt (80KB)
    unsigned short* Wh = (unsigned short*)d_ws;
    float* biasArr = (float*)((char*)d_ws + 3 * HF * HF * sizeof(unsigned short));
    int* cnt = (int*)((char*)d_ws + 3 * HF * HF * sizeof(unsigned short) + 3 * HF * sizeof(float));

    const int* srcI = ei;        // edge_index[0]
    const int* dstI = ei + E;    // edge_index[1]

    // x16 (5.12MB) parked in the agg region (dead until after GEMM1)
    unsigned short* x16 = (unsigned short*)d_out;

    cvt_x_kernel<<<(Nn * IN_F / 4 + 255) / 256, 256, 0, stream>>>(x, x16, Nn * IN_F / 4);
    prep_kernel<<<3 * HF, HF, 0, stream>>>(W0, b0, g0, beta0, m0, v0,
                                           Ws, bs, gs, betas, ms, vs, Wh, biasArr);
    hipMemsetAsync(cnt, 0, (size_t)Nn * sizeof(int), stream);
    count_kernel<<<(E + 255) / 256, 256, 0, stream>>>(dstI, cnt, E);

    gemm_kernel<0><<<E / 128, 512, 0, stream>>>(x16, hhB, dstI, srcI,
                                                Wh, biasArr, hhB, nullptr);
    hipMemsetAsync(agg, 0, (size_t)Nn * HF * sizeof(float), stream);   // x16 dead now
    gemm_kernel<1><<<E / 128, 512, 0, stream>>>(x16, hhB, dstI, srcI,
                                                Wh + HF * HF, biasArr + HF, hhB, nullptr);
    gemm_kernel<2><<<E / 128, 512, 0, stream>>>(x16, hhB, dstI, srcI,
                                                Wh + 2 * HF * HF, biasArr + 2 * HF,
                                                (unsigned char*)hptr, agg);

    finalize_kernel<<<Nn, HF, 0, stream>>>(agg, cnt);
}